// Round 5
// baseline (1401.255 us; speedup 1.0000x reference)
//
#include <hip/hip_runtime.h>
#include <math.h>

// B=32, Lq=Lk=D=1024
#define BM 128
#define BN 128
#define BK 32
#define KP 40   // padded LDS K-stride in bf16 elems (80B rows, 16B-aligned frags)

typedef __bf16 bf16x8 __attribute__((ext_vector_type(8)));
typedef float  floatx4 __attribute__((ext_vector_type(4)));
typedef unsigned short u16;

__device__ __forceinline__ u16 f2bf(float x) {
    unsigned int u = __float_as_uint(x);
    u += 0x7FFFu + ((u >> 16) & 1u);           // RNE
    return (u16)(u >> 16);
}
__device__ __forceinline__ float bf2f(u16 h) {
    return __uint_as_float(((unsigned int)h) << 16);
}

// Barrier that does NOT drain vmcnt: LDS consistency needs only lgkmcnt(0).
// In-flight global loads (register destinations) stay outstanding across the
// barrier; the compiler's register-dependency tracking inserts the vmcnt wait
// at first use. This is what lets the 2-deep prefetch actually cover ~900 cy
// of HBM latency (__syncthreads would force vmcnt(0) here and kill it).
__device__ __forceinline__ void bar_lds() {
    asm volatile("s_waitcnt lgkmcnt(0)" ::: "memory");
    __builtin_amdgcn_s_barrier();
}

// convert float4 -> hi (and optionally lo) bf16 quads, store 8B each into LDS
template <bool LO>
__device__ __forceinline__ void cvt_store(u16* H, u16* L, int idx, float4 v) {
    u16 h0 = f2bf(v.x), h1 = f2bf(v.y), h2 = f2bf(v.z), h3 = f2bf(v.w);
    *(ushort4*)(H + idx) = make_ushort4(h0, h1, h2, h3);
    if (LO) {
        u16 l0 = f2bf(v.x - bf2f(h0)), l1 = f2bf(v.y - bf2f(h1));
        u16 l2 = f2bf(v.z - bf2f(h2)), l3 = f2bf(v.w - bf2f(h3));
        *(ushort4*)(L + idx) = make_ushort4(l0, l1, l2, l3);
    }
}

enum OpMode { OP_F32 = 0, OP_PLANES = 1, OP_BF16 = 2 };

// ---------------------------------------------------------------------------
// MFMA GEMM, NT: C[M,N] = A[M,K] * B[N,K]^T
// EPI:   0 fp32 store, 1 length-masked fp32, 2 tanh fp32, 3 bf16 hi/lo planes,
//        4 bf16 store
// SOFTA: A elements softmax'd on the fly (AMODE==OP_F32 only)
// SPLITA: A is two concatenated K-halves (AMODE==OP_BF16: A=half0, A2=half1)
// TRANSB: B is fp32 [K][N] row-major (NN GEMM); staged as TRANSPOSED bf16
// NPASS: 3 = hi/lo split-bf16 (fp32-grade), 1 = plain bf16
// AMODE/BMODE: OP_F32 / OP_PLANES / OP_BF16
//
// 2-deep register prefetch + lgkmcnt-only barriers: loads for tile t+2 issue
// right after tile t's staging barrier and remain in flight across BOTH
// barriers (no vmcnt drain), completing just before their stage phase.
// ---------------------------------------------------------------------------
template <int EPI, bool SOFTA, bool SPLITA, bool TRANSB, int NPASS, int AMODE, int BMODE>
__global__ __launch_bounds__(256, 2) void mfma_gemm(
    const void* __restrict__ Av, const void* __restrict__ A2v,
    const void* __restrict__ Bv, const void* __restrict__ B2v,
    void* __restrict__ Cv, void* __restrict__ C2v,
    int K, int lda, int ldb, int ldc,
    long long aBatch, long long bBatch, long long cBatch,
    const float2* __restrict__ stats, long long statsBatch,
    const int* __restrict__ qlen, const int* __restrict__ klen)
{
    const int b = blockIdx.z;

    // typed, batch-offset base pointers (unused ones are dead code per mode)
    const float* A_f  = (const float*)Av + aBatch * b;
    const u16*   A_h  = (const u16*)Av + aBatch * b;
    const u16*   A_l  = (const u16*)A2v + aBatch * b;   // OP_PLANES lo plane
    const u16*   A2_h = (const u16*)A2v;                // OP_BF16 + SPLITA half-2
    const float* B_f  = (const float*)Bv + bBatch * b;
    const u16*   B_h  = (const u16*)Bv + bBatch * b;
    const u16*   B_l  = (const u16*)B2v + bBatch * b;

    constexpr int LP = (NPASS == 3) ? 2 : 1;
    __shared__ __align__(16) u16 smem[(BM + BN) * KP * LP];
    u16* Ah = smem;
    u16* Al = Ah + (NPASS == 3 ? BM * KP : 0);
    u16* Bh = Ah + BM * KP * LP;
    u16* Bl = Bh + (NPASS == 3 ? BN * KP : 0);

    const int tid = threadIdx.x;
    const int m0 = blockIdx.y * BM;
    const int n0 = blockIdx.x * BN;

    // staging indices (K-contig operands)
    const int sr = tid >> 3;                  // 0..31
    const int sc = (tid & 7) << 2;            // 0,4,...,28

    // wave / lane MFMA indices
    const int wv = tid >> 6;
    const int wm = (wv >> 1) << 6;            // 0 or 64
    const int wn = (wv & 1) << 6;
    const int lane = tid & 63;
    const int lm = lane & 15;
    const int lk = (lane >> 4) << 3;          // 0,8,16,24

    floatx4 acc[4][4];
#pragma unroll
    for (int i = 0; i < 4; i++)
#pragma unroll
        for (int j = 0; j < 4; j++) acc[i][j] = (floatx4)0.f;

    float2 st[4];
    if (SOFTA) {
        const float2* sp = stats + statsBatch * b;
#pragma unroll
        for (int r = 0; r < 4; r++) st[r] = sp[m0 + (r << 5) + sr];
    }

    // prefetch register sets (mode-specific members; unused ones are DCE'd)
    struct PF {
        float4  vaf[4]; ushort4 vah[4], vaL[4];
        float4  vbf[4]; ushort4 vbh[4], vbL[4];
    };

    auto ldA = [&](int k0, PF& r_) {
        if constexpr (AMODE == OP_F32) {
#pragma unroll
            for (int r = 0; r < 4; r++) {
                const int row = (r << 5) + sr;
                r_.vaf[r] = *(const float4*)(A_f + (size_t)(m0 + row) * lda + k0 + sc);
            }
        } else if constexpr (AMODE == OP_PLANES) {
#pragma unroll
            for (int r = 0; r < 4; r++) {
                const int row = (r << 5) + sr;
                const size_t off = (size_t)(m0 + row) * lda + k0 + sc;
                r_.vah[r] = *(const ushort4*)(A_h + off);
                r_.vaL[r] = *(const ushort4*)(A_l + off);
            }
        } else {                               // OP_BF16 (optionally SPLITA)
            const u16* Ap = A_h;
            int kk = k0;
            if constexpr (SPLITA) {
                const int half = K >> 1;
                Ap = (k0 < half) ? A_h : A2_h;
                kk = k0 & (half - 1);
            }
#pragma unroll
            for (int r = 0; r < 4; r++) {
                const int row = (r << 5) + sr;
                r_.vah[r] = *(const ushort4*)(Ap + (size_t)(m0 + row) * lda + kk + sc);
            }
        }
    };
    auto ldB = [&](int k0, PF& r_) {
        if constexpr (TRANSB) {
            const int kr = tid >> 3;
            const int c4 = (tid & 7) << 2;
#pragma unroll
            for (int r = 0; r < 4; r++) {
                const int col = (r << 5) + c4;
                const float* src = B_f + (size_t)(k0 + kr) * ldb + n0 + col;
                float2 v0 = *(const float2*)(src);
                float2 v1 = *(const float2*)(src + 2);
                r_.vbf[r] = make_float4(v0.x, v0.y, v1.x, v1.y);
            }
        } else if constexpr (BMODE == OP_F32) {
#pragma unroll
            for (int r = 0; r < 4; r++) {
                const int row = (r << 5) + sr;
                r_.vbf[r] = *(const float4*)(B_f + (size_t)(n0 + row) * ldb + k0 + sc);
            }
        } else if constexpr (BMODE == OP_PLANES) {
#pragma unroll
            for (int r = 0; r < 4; r++) {
                const int row = (r << 5) + sr;
                const size_t off = (size_t)(n0 + row) * ldb + k0 + sc;
                r_.vbh[r] = *(const ushort4*)(B_h + off);
                r_.vbL[r] = *(const ushort4*)(B_l + off);
            }
        } else {                               // OP_BF16
#pragma unroll
            for (int r = 0; r < 4; r++) {
                const int row = (r << 5) + sr;
                r_.vbh[r] = *(const ushort4*)(B_h + (size_t)(n0 + row) * ldb + k0 + sc);
            }
        }
    };
    auto stA = [&](const PF& r_) {
#pragma unroll
        for (int r = 0; r < 4; r++) {
            const int idx = ((r << 5) + sr) * KP + sc;
            if constexpr (AMODE == OP_F32) {
                float4 v = r_.vaf[r];
                if (SOFTA) {
                    v.x = expf(v.x - st[r].x) * st[r].y;
                    v.y = expf(v.y - st[r].x) * st[r].y;
                    v.z = expf(v.z - st[r].x) * st[r].y;
                    v.w = expf(v.w - st[r].x) * st[r].y;
                }
                cvt_store<NPASS == 3>(Ah, Al, idx, v);
            } else if constexpr (AMODE == OP_PLANES) {
                *(ushort4*)(Ah + idx) = r_.vah[r];
                *(ushort4*)(Al + idx) = r_.vaL[r];
            } else {
                *(ushort4*)(Ah + idx) = r_.vah[r];
            }
        }
    };
    auto stB = [&](const PF& r_) {
        if constexpr (TRANSB) {
            const int kr = tid >> 3;
            const int c4 = (tid & 7) << 2;
#pragma unroll
            for (int r = 0; r < 4; r++) {
                const int col = (r << 5) + c4;
                const float4 v = r_.vbf[r];
                Bh[(col + 0) * KP + kr] = f2bf(v.x);   // transposed bf16 scatter
                Bh[(col + 1) * KP + kr] = f2bf(v.y);
                Bh[(col + 2) * KP + kr] = f2bf(v.z);
                Bh[(col + 3) * KP + kr] = f2bf(v.w);
            }
        } else {
#pragma unroll
            for (int r = 0; r < 4; r++) {
                const int idx = ((r << 5) + sr) * KP + sc;
                if constexpr (BMODE == OP_F32) {
                    cvt_store<NPASS == 3>(Bh, Bl, idx, r_.vbf[r]);
                } else if constexpr (BMODE == OP_PLANES) {
                    *(ushort4*)(Bh + idx) = r_.vbh[r];
                    *(ushort4*)(Bl + idx) = r_.vbL[r];
                } else {
                    *(ushort4*)(Bh + idx) = r_.vbh[r];
                }
            }
        }
    };
    auto frags_mfma = [&]() {
        bf16x8 ah[4], al[4], bh[4], bl[4];
#pragma unroll
        for (int t = 0; t < 4; t++) {
            const int ar = (wm + (t << 4) + lm) * KP + lk;
            ah[t] = *(const bf16x8*)(Ah + ar);
            if constexpr (NPASS == 3) al[t] = *(const bf16x8*)(Al + ar);
        }
#pragma unroll
        for (int t = 0; t < 4; t++) {
            const int br = (wn + (t << 4) + lm) * KP + lk;
            bh[t] = *(const bf16x8*)(Bh + br);
            if constexpr (NPASS == 3) bl[t] = *(const bf16x8*)(Bl + br);
        }
#pragma unroll
        for (int i = 0; i < 4; i++)
#pragma unroll
            for (int j = 0; j < 4; j++) {
                if constexpr (NPASS == 3) {
                    acc[i][j] = __builtin_amdgcn_mfma_f32_16x16x32_bf16(al[i], bh[j], acc[i][j], 0, 0, 0);
                    acc[i][j] = __builtin_amdgcn_mfma_f32_16x16x32_bf16(ah[i], bl[j], acc[i][j], 0, 0, 0);
                }
                acc[i][j] = __builtin_amdgcn_mfma_f32_16x16x32_bf16(ah[i], bh[j], acc[i][j], 0, 0, 0);
            }
    };

    // ---- 2-deep prologue (K is a multiple of 2*BK, and K >= 2*BK) ----
    PF r0, r1;
    ldA(0, r0);  ldB(0, r0);
    ldA(BK, r1); ldB(BK, r1);

    for (int k0 = 0; k0 < K; k0 += 2 * BK) {
        // ---- tile t (r0) ----
        stA(r0); stB(r0);
        bar_lds();
        if (k0 + 2 * BK < K) { ldA(k0 + 2 * BK, r0); ldB(k0 + 2 * BK, r0); }
        frags_mfma();
        bar_lds();
        // ---- tile t+1 (r1) ----
        stA(r1); stB(r1);
        bar_lds();
        if (k0 + 3 * BK < K) { ldA(k0 + 3 * BK, r1); ldB(k0 + 3 * BK, r1); }
        frags_mfma();
        bar_lds();
    }

    // ---- epilogue ----
    float* C_f = (float*)Cv + cBatch * b;
    u16*   C_h = (u16*)Cv + cBatch * b;
    u16*   C_l = (u16*)C2v + cBatch * b;
    int qb = 0, kb = 0;
    if (EPI == 1) { qb = qlen[b]; kb = klen[b]; }
    const int qd = (lane >> 4) << 2;
#pragma unroll
    for (int i = 0; i < 4; i++)
#pragma unroll
        for (int j = 0; j < 4; j++) {
            const int col = n0 + wn + (j << 4) + lm;
#pragma unroll
            for (int r = 0; r < 4; r++) {
                const int row = m0 + wm + (i << 4) + qd + r;
                const size_t off = (size_t)row * ldc + col;
                float v = acc[i][j][r];
                if constexpr (EPI == 0) {
                    C_f[off] = v;
                } else if constexpr (EPI == 1) {
                    C_f[off] = (row < qb && col < kb) ? v : -1e9f;
                } else if constexpr (EPI == 2) {
                    C_f[off] = tanhf(v);
                } else if constexpr (EPI == 3) {
                    const u16 h = f2bf(v);
                    C_h[off] = h;
                    C_l[off] = f2bf(v - bf2f(h));
                } else {
                    C_h[off] = f2bf(v);
                }
            }
        }
}

// ---------------------------------------------------------------------------
// Per-row softmax stats: stats[row] = (rowmax, 1/sum(exp(x-max)))
// ---------------------------------------------------------------------------
__global__ __launch_bounds__(256) void row_stats_kernel(
    const float* __restrict__ S, float2* __restrict__ stats, int L)
{
    const int row = blockIdx.x * 4 + (threadIdx.x >> 6);
    const int lane = threadIdx.x & 63;
    const float* p = S + (size_t)row * L;

    float mx = -1e30f;
    for (int j = lane; j < L; j += 64) mx = fmaxf(mx, p[j]);
#pragma unroll
    for (int off = 32; off > 0; off >>= 1) mx = fmaxf(mx, __shfl_xor(mx, off, 64));

    float sm = 0.f;
    for (int j = lane; j < L; j += 64) sm += expf(p[j] - mx);
#pragma unroll
    for (int off = 32; off > 0; off >>= 1) sm += __shfl_xor(sm, off, 64);

    if (lane == 0) stats[row] = make_float2(mx, 1.f / sm);
}

// ---------------------------------------------------------------------------
// Weight prepasses: fp32 -> bf16 hi/lo planes, fp32 -> bf16
// ---------------------------------------------------------------------------
__global__ __launch_bounds__(256) void cvt_hilo_kernel(
    const float* __restrict__ s, u16* __restrict__ hi, u16* __restrict__ lo, int n4)
{
    const int stride = gridDim.x * 256;
    for (int i = blockIdx.x * 256 + threadIdx.x; i < n4; i += stride) {
        float4 v = ((const float4*)s)[i];
        u16 h0 = f2bf(v.x), h1 = f2bf(v.y), h2 = f2bf(v.z), h3 = f2bf(v.w);
        ((ushort4*)hi)[i] = make_ushort4(h0, h1, h2, h3);
        ((ushort4*)lo)[i] = make_ushort4(f2bf(v.x - bf2f(h0)), f2bf(v.y - bf2f(h1)),
                                         f2bf(v.z - bf2f(h2)), f2bf(v.w - bf2f(h3)));
    }
}
__global__ __launch_bounds__(256) void cvt_bf16_kernel(
    const float* __restrict__ s, u16* __restrict__ d, int n4)
{
    const int stride = gridDim.x * 256;
    for (int i = blockIdx.x * 256 + threadIdx.x; i < n4; i += stride) {
        float4 v = ((const float4*)s)[i];
        ((ushort4*)d)[i] = make_ushort4(f2bf(v.x), f2bf(v.y), f2bf(v.z), f2bf(v.w));
    }
}

// ---------------------------------------------------------------------------
extern "C" void kernel_launch(void* const* d_in, const int* in_sizes, int n_in,
                              void* d_out, int out_size, void* d_ws, size_t ws_size,
                              hipStream_t stream)
{
    const float* query   = (const float*)d_in[0];   // [B,Lq,D]
    const float* context = (const float*)d_in[1];   // [B,Lk,D]
    const int*   qlens   = (const int*)d_in[2];     // [B]
    const int*   clens   = (const int*)d_in[3];     // [B]
    const float* W_in    = (const float*)d_in[4];   // [D,D]
    const float* W_out   = (const float*)d_in[5];   // [D,2D]

    const int B = 32, Lq = 1024, Lk = 1024, D = 1024;
    const long long nQ = (long long)B * Lq * D;     // 33,554,432

    float* out    = (float*)d_out;                  // [B,Lq,D]
    float* scores = out + nQ;                       // [B,Lq,Lk]

    // workspace: 3x 64MiB bf16 planes + 8MiB weights + stats = 200.25 MiB
    u16* q_hi    = (u16*)d_ws;                      // 64 MiB
    u16* q_lo    = q_hi + nQ;                       // 64 MiB
    u16* mixb    = q_lo + nQ;                       // 64 MiB
    u16* w_in_hi = mixb + nQ;                       // 2 MiB
    u16* w_in_lo = w_in_hi + (1 << 20);             // 2 MiB
    u16* w_out_b = w_in_lo + (1 << 20);             // 4 MiB
    float2* stats = (float2*)(w_out_b + (2 << 20)); // 256 KiB

    // 0) weight prepasses (~6 us)
    cvt_hilo_kernel<<<1024, 256, 0, stream>>>(W_in, w_in_hi, w_in_lo, (D * D) / 4);
    cvt_bf16_kernel<<<2048, 256, 0, stream>>>(W_out, w_out_b, (D * 2 * D) / 4);

    // 1) q_hi/q_lo = split(query @ W_in^T)  (3-pass; B pre-split planes)
    mfma_gemm<3, false, false, false, 3, OP_F32, OP_PLANES>
        <<<dim3(D / BN, (B * Lq) / BM, 1), 256, 0, stream>>>(
        query, nullptr, w_in_hi, w_in_lo, q_hi, q_lo,
        D, D, D, D, 0LL, 0LL, 0LL, nullptr, 0LL, nullptr, nullptr);

    // 2) scores_m = mask(q @ ctx^T)  (batched NT, 3-pass; A pre-split planes)
    mfma_gemm<1, false, false, false, 3, OP_PLANES, OP_F32>
        <<<dim3(Lk / BN, Lq / BM, B), 256, 0, stream>>>(
        q_hi, q_lo, context, nullptr, scores, nullptr,
        D, D, D, Lk, (long long)Lq * D, (long long)Lk * D, (long long)Lq * Lk,
        nullptr, 0LL, qlens, clens);

    // 3) per-row softmax stats
    row_stats_kernel<<<(B * Lq) / 4, 256, 0, stream>>>(scores, stats, Lk);

    // 4) mixb = bf16(softmax(scores) @ ctx)  (batched NN; transposed-bf16 B staging)
    mfma_gemm<4, true, false, true, 1, OP_F32, OP_F32>
        <<<dim3(D / BN, Lq / BM, B), 256, 0, stream>>>(
        scores, nullptr, context, nullptr, mixb, nullptr,
        Lk, Lk, D, D, (long long)Lq * Lk, (long long)Lk * D, (long long)Lq * D,
        stats, (long long)Lq, nullptr, nullptr);

    // 5) out = tanh([mixb | q_hi] @ w_out_b^T)  (K=2048 split-A, all-bf16 operands)
    mfma_gemm<2, false, true, false, 1, OP_BF16, OP_BF16>
        <<<dim3(D / BN, (B * Lq) / BM, 1), 256, 0, stream>>>(
        mixb, q_hi, w_out_b, nullptr, out, nullptr,
        2 * D, D, 2 * D, D, 0LL, 0LL, 0LL, nullptr, 0LL, nullptr, nullptr);
}

// Round 6
// 1305.173 us; speedup vs baseline: 1.0736x; 1.0736x over previous
//
#include <hip/hip_runtime.h>
#include <math.h>

// B=32, Lq=Lk=D=1024
#define BM 128
#define BN 128
#define BK 32
#define KP 40   // padded LDS K-stride in bf16 elems (80B rows, 16B-aligned frags)

typedef __bf16 bf16x8 __attribute__((ext_vector_type(8)));
typedef float  floatx4 __attribute__((ext_vector_type(4)));
typedef unsigned short u16;

__device__ __forceinline__ u16 f2bf(float x) {
    unsigned int u = __float_as_uint(x);
    u += 0x7FFFu + ((u >> 16) & 1u);           // RNE
    return (u16)(u >> 16);
}
__device__ __forceinline__ float bf2f(u16 h) {
    return __uint_as_float(((unsigned int)h) << 16);
}

// Barrier that does NOT drain vmcnt: LDS consistency needs only lgkmcnt(0).
__device__ __forceinline__ void bar_lds() {
    asm volatile("s_waitcnt lgkmcnt(0)" ::: "memory");
    __builtin_amdgcn_s_barrier();
}

// convert float4 -> hi (and optionally lo) bf16 quads, store 8B each into LDS
template <bool LO>
__device__ __forceinline__ void cvt_store(u16* H, u16* L, int idx, float4 v) {
    u16 h0 = f2bf(v.x), h1 = f2bf(v.y), h2 = f2bf(v.z), h3 = f2bf(v.w);
    *(ushort4*)(H + idx) = make_ushort4(h0, h1, h2, h3);
    if (LO) {
        u16 l0 = f2bf(v.x - bf2f(h0)), l1 = f2bf(v.y - bf2f(h1));
        u16 l2 = f2bf(v.z - bf2f(h2)), l3 = f2bf(v.w - bf2f(h3));
        *(ushort4*)(L + idx) = make_ushort4(l0, l1, l2, l3);
    }
}

enum OpMode { OP_F32 = 0, OP_PLANES = 1, OP_BF16 = 2 };

// ---------------------------------------------------------------------------
// MFMA GEMM, NT: C[M,N] = A[M,K] * B[N,K]^T
// EPI:   0 fp32 store, 1 length-masked fp32, 2 tanh fp32, 3 bf16 hi/lo planes,
//        4 bf16 store
// SOFTA: A elements softmax'd on the fly (AMODE==OP_F32 only)
// SPLITA: A is two concatenated K-halves
// TRANSB: B is fp32 [K][N] row-major (NN GEMM); staged as TRANSPOSED bf16
// NPASS: 3 = hi/lo split-bf16 (fp32-grade), 1 = plain bf16
//
// Length-mask work skipping:
//  * EPI==1: a tile with m0>=qlen or n0>=klen is entirely -1e9 -> store the
//    constant and return before any loads (expected ~68% of score tiles).
//  * SOFTA: if ALL rows of the tile are valid (m0+BM<=qlen), softmax weights
//    for k>=klen are EXACTLY 0 in fp32 (expf underflow * rinv), so K-tiles
//    beyond klen (rounded up to the 2*BK step) are skipped - bit-exact.
//    Fully-masked rows (uniform 1/Lk weights over ALL k) keep full K.
// ---------------------------------------------------------------------------
template <int EPI, bool SOFTA, bool SPLITA, bool TRANSB, int NPASS, int AMODE, int BMODE>
__global__ __launch_bounds__(256, 2) void mfma_gemm(
    const void* __restrict__ Av, const void* __restrict__ A2v,
    const void* __restrict__ Bv, const void* __restrict__ B2v,
    void* __restrict__ Cv, void* __restrict__ C2v,
    int K, int lda, int ldb, int ldc,
    long long aBatch, long long bBatch, long long cBatch,
    const float2* __restrict__ stats, long long statsBatch,
    const int* __restrict__ qlen, const int* __restrict__ klen)
{
    const int b = blockIdx.z;

    const int tid = threadIdx.x;
    const int m0 = blockIdx.y * BM;
    const int n0 = blockIdx.x * BN;

    // wave / lane MFMA indices
    const int wv = tid >> 6;
    const int wm = (wv >> 1) << 6;            // 0 or 64
    const int wn = (wv & 1) << 6;
    const int lane = tid & 63;
    const int lm = lane & 15;
    const int lk = (lane >> 4) << 3;          // 0,8,16,24
    const int qd = (lane >> 4) << 2;

    // ---- masked-tile fast path (scores GEMM): whole tile is -1e9 ----
    int qb = 0, kb = 0;
    if constexpr (EPI == 1) {
        qb = qlen[b]; kb = klen[b];
        if (m0 >= qb || n0 >= kb) {
            float* C_f0 = (float*)Cv + cBatch * b;
#pragma unroll
            for (int i = 0; i < 4; i++)
#pragma unroll
                for (int j = 0; j < 4; j++) {
                    const int col = n0 + wn + (j << 4) + lm;
#pragma unroll
                    for (int r = 0; r < 4; r++) {
                        const int row = m0 + wm + (i << 4) + qd + r;
                        C_f0[(size_t)row * ldc + col] = -1e9f;
                    }
                }
            return;
        }
    }

    // ---- SOFTA K-truncation: zero-weight K-tiles skipped when exact ----
    int Kend = K;
    if constexpr (SOFTA) {
        const int ql2 = qlen[b];
        if (m0 + BM <= ql2) {                 // every row valid -> w[k>=kl] == 0
            const int kl2 = klen[b];
            int ke = ((kl2 + 2 * BK - 1) / (2 * BK)) * (2 * BK);
            Kend = ke < K ? ke : K;
        }
    }

    // typed, batch-offset base pointers (unused ones are dead code per mode)
    const float* A_f  = (const float*)Av + aBatch * b;
    const u16*   A_h  = (const u16*)Av + aBatch * b;
    const u16*   A_l  = (const u16*)A2v + aBatch * b;   // OP_PLANES lo plane
    const u16*   A2_h = (const u16*)A2v;                // OP_BF16 + SPLITA half-2
    const float* B_f  = (const float*)Bv + bBatch * b;
    const u16*   B_h  = (const u16*)Bv + bBatch * b;
    const u16*   B_l  = (const u16*)B2v + bBatch * b;

    constexpr int LP = (NPASS == 3) ? 2 : 1;
    __shared__ __align__(16) u16 smem[(BM + BN) * KP * LP];
    u16* Ah = smem;
    u16* Al = Ah + (NPASS == 3 ? BM * KP : 0);
    u16* Bh = Ah + BM * KP * LP;
    u16* Bl = Bh + (NPASS == 3 ? BN * KP : 0);

    // staging indices (K-contig operands)
    const int sr = tid >> 3;                  // 0..31
    const int sc = (tid & 7) << 2;            // 0,4,...,28

    floatx4 acc[4][4];
#pragma unroll
    for (int i = 0; i < 4; i++)
#pragma unroll
        for (int j = 0; j < 4; j++) acc[i][j] = (floatx4)0.f;

    float2 st[4];
    if (SOFTA) {
        const float2* sp = stats + statsBatch * b;
#pragma unroll
        for (int r = 0; r < 4; r++) st[r] = sp[m0 + (r << 5) + sr];
    }

    // prefetch register sets (mode-specific members; unused ones are DCE'd)
    struct PF {
        float4  vaf[4]; ushort4 vah[4], vaL[4];
        float4  vbf[4]; ushort4 vbh[4], vbL[4];
    };

    auto ldA = [&](int k0, PF& r_) {
        if constexpr (AMODE == OP_F32) {
#pragma unroll
            for (int r = 0; r < 4; r++) {
                const int row = (r << 5) + sr;
                r_.vaf[r] = *(const float4*)(A_f + (size_t)(m0 + row) * lda + k0 + sc);
            }
        } else if constexpr (AMODE == OP_PLANES) {
#pragma unroll
            for (int r = 0; r < 4; r++) {
                const int row = (r << 5) + sr;
                const size_t off = (size_t)(m0 + row) * lda + k0 + sc;
                r_.vah[r] = *(const ushort4*)(A_h + off);
                r_.vaL[r] = *(const ushort4*)(A_l + off);
            }
        } else {                               // OP_BF16 (optionally SPLITA)
            const u16* Ap = A_h;
            int kk = k0;
            if constexpr (SPLITA) {
                const int half = K >> 1;
                Ap = (k0 < half) ? A_h : A2_h;
                kk = k0 & (half - 1);
            }
#pragma unroll
            for (int r = 0; r < 4; r++) {
                const int row = (r << 5) + sr;
                r_.vah[r] = *(const ushort4*)(Ap + (size_t)(m0 + row) * lda + kk + sc);
            }
        }
    };
    auto ldB = [&](int k0, PF& r_) {
        if constexpr (TRANSB) {
            const int kr = tid >> 3;
            const int c4 = (tid & 7) << 2;
#pragma unroll
            for (int r = 0; r < 4; r++) {
                const int col = (r << 5) + c4;
                const float* src = B_f + (size_t)(k0 + kr) * ldb + n0 + col;
                float2 v0 = *(const float2*)(src);
                float2 v1 = *(const float2*)(src + 2);
                r_.vbf[r] = make_float4(v0.x, v0.y, v1.x, v1.y);
            }
        } else if constexpr (BMODE == OP_F32) {
#pragma unroll
            for (int r = 0; r < 4; r++) {
                const int row = (r << 5) + sr;
                r_.vbf[r] = *(const float4*)(B_f + (size_t)(n0 + row) * ldb + k0 + sc);
            }
        } else if constexpr (BMODE == OP_PLANES) {
#pragma unroll
            for (int r = 0; r < 4; r++) {
                const int row = (r << 5) + sr;
                const size_t off = (size_t)(n0 + row) * ldb + k0 + sc;
                r_.vbh[r] = *(const ushort4*)(B_h + off);
                r_.vbL[r] = *(const ushort4*)(B_l + off);
            }
        } else {                               // OP_BF16
#pragma unroll
            for (int r = 0; r < 4; r++) {
                const int row = (r << 5) + sr;
                r_.vbh[r] = *(const ushort4*)(B_h + (size_t)(n0 + row) * ldb + k0 + sc);
            }
        }
    };
    auto stA = [&](const PF& r_) {
#pragma unroll
        for (int r = 0; r < 4; r++) {
            const int idx = ((r << 5) + sr) * KP + sc;
            if constexpr (AMODE == OP_F32) {
                float4 v = r_.vaf[r];
                if (SOFTA) {
                    v.x = expf(v.x - st[r].x) * st[r].y;
                    v.y = expf(v.y - st[r].x) * st[r].y;
                    v.z = expf(v.z - st[r].x) * st[r].y;
                    v.w = expf(v.w - st[r].x) * st[r].y;
                }
                cvt_store<NPASS == 3>(Ah, Al, idx, v);
            } else if constexpr (AMODE == OP_PLANES) {
                *(ushort4*)(Ah + idx) = r_.vah[r];
                *(ushort4*)(Al + idx) = r_.vaL[r];
            } else {
                *(ushort4*)(Ah + idx) = r_.vah[r];
            }
        }
    };
    auto stB = [&](const PF& r_) {
        if constexpr (TRANSB) {
            const int kr = tid >> 3;
            const int c4 = (tid & 7) << 2;
#pragma unroll
            for (int r = 0; r < 4; r++) {
                const int col = (r << 5) + c4;
                const float4 v = r_.vbf[r];
                Bh[(col + 0) * KP + kr] = f2bf(v.x);   // transposed bf16 scatter
                Bh[(col + 1) * KP + kr] = f2bf(v.y);
                Bh[(col + 2) * KP + kr] = f2bf(v.z);
                Bh[(col + 3) * KP + kr] = f2bf(v.w);
            }
        } else {
#pragma unroll
            for (int r = 0; r < 4; r++) {
                const int idx = ((r << 5) + sr) * KP + sc;
                if constexpr (BMODE == OP_F32) {
                    cvt_store<NPASS == 3>(Bh, Bl, idx, r_.vbf[r]);
                } else if constexpr (BMODE == OP_PLANES) {
                    *(ushort4*)(Bh + idx) = r_.vbh[r];
                    *(ushort4*)(Bl + idx) = r_.vbL[r];
                } else {
                    *(ushort4*)(Bh + idx) = r_.vbh[r];
                }
            }
        }
    };
    auto frags_mfma = [&]() {
        bf16x8 ah[4], al[4], bh[4], bl[4];
#pragma unroll
        for (int t = 0; t < 4; t++) {
            const int ar = (wm + (t << 4) + lm) * KP + lk;
            ah[t] = *(const bf16x8*)(Ah + ar);
            if constexpr (NPASS == 3) al[t] = *(const bf16x8*)(Al + ar);
        }
#pragma unroll
        for (int t = 0; t < 4; t++) {
            const int br = (wn + (t << 4) + lm) * KP + lk;
            bh[t] = *(const bf16x8*)(Bh + br);
            if constexpr (NPASS == 3) bl[t] = *(const bf16x8*)(Bl + br);
        }
#pragma unroll
        for (int i = 0; i < 4; i++)
#pragma unroll
            for (int j = 0; j < 4; j++) {
                if constexpr (NPASS == 3) {
                    acc[i][j] = __builtin_amdgcn_mfma_f32_16x16x32_bf16(al[i], bh[j], acc[i][j], 0, 0, 0);
                    acc[i][j] = __builtin_amdgcn_mfma_f32_16x16x32_bf16(ah[i], bl[j], acc[i][j], 0, 0, 0);
                }
                acc[i][j] = __builtin_amdgcn_mfma_f32_16x16x32_bf16(ah[i], bh[j], acc[i][j], 0, 0, 0);
            }
    };

    // ---- 2-deep prologue (Kend is a multiple of 2*BK, Kend >= 2*BK) ----
    PF r0, r1;
    ldA(0, r0);  ldB(0, r0);
    ldA(BK, r1); ldB(BK, r1);

    for (int k0 = 0; k0 < Kend; k0 += 2 * BK) {
        // ---- tile t (r0) ----
        stA(r0); stB(r0);
        bar_lds();
        if (k0 + 2 * BK < Kend) { ldA(k0 + 2 * BK, r0); ldB(k0 + 2 * BK, r0); }
        frags_mfma();
        bar_lds();
        // ---- tile t+1 (r1) ----
        stA(r1); stB(r1);
        bar_lds();
        if (k0 + 3 * BK < Kend) { ldA(k0 + 3 * BK, r1); ldB(k0 + 3 * BK, r1); }
        frags_mfma();
        bar_lds();
    }

    // ---- epilogue ----
    float* C_f = (float*)Cv + cBatch * b;
    u16*   C_h = (u16*)Cv + cBatch * b;
    u16*   C_l = (u16*)C2v + cBatch * b;
#pragma unroll
    for (int i = 0; i < 4; i++)
#pragma unroll
        for (int j = 0; j < 4; j++) {
            const int col = n0 + wn + (j << 4) + lm;
#pragma unroll
            for (int r = 0; r < 4; r++) {
                const int row = m0 + wm + (i << 4) + qd + r;
                const size_t off = (size_t)row * ldc + col;
                float v = acc[i][j][r];
                if constexpr (EPI == 0) {
                    C_f[off] = v;
                } else if constexpr (EPI == 1) {
                    C_f[off] = (row < qb && col < kb) ? v : -1e9f;
                } else if constexpr (EPI == 2) {
                    C_f[off] = tanhf(v);
                } else if constexpr (EPI == 3) {
                    const u16 h = f2bf(v);
                    C_h[off] = h;
                    C_l[off] = f2bf(v - bf2f(h));
                } else {
                    C_h[off] = f2bf(v);
                }
            }
        }
}

// ---------------------------------------------------------------------------
// Per-row softmax stats: stats[row] = (rowmax, 1/sum(exp(x-max)))
// ---------------------------------------------------------------------------
__global__ __launch_bounds__(256) void row_stats_kernel(
    const float* __restrict__ S, float2* __restrict__ stats, int L)
{
    const int row = blockIdx.x * 4 + (threadIdx.x >> 6);
    const int lane = threadIdx.x & 63;
    const float* p = S + (size_t)row * L;

    float mx = -1e30f;
    for (int j = lane; j < L; j += 64) mx = fmaxf(mx, p[j]);
#pragma unroll
    for (int off = 32; off > 0; off >>= 1) mx = fmaxf(mx, __shfl_xor(mx, off, 64));

    float sm = 0.f;
    for (int j = lane; j < L; j += 64) sm += expf(p[j] - mx);
#pragma unroll
    for (int off = 32; off > 0; off >>= 1) sm += __shfl_xor(sm, off, 64);

    if (lane == 0) stats[row] = make_float2(mx, 1.f / sm);
}

// ---------------------------------------------------------------------------
// Weight prepasses: fp32 -> bf16 hi/lo planes, fp32 -> bf16
// ---------------------------------------------------------------------------
__global__ __launch_bounds__(256) void cvt_hilo_kernel(
    const float* __restrict__ s, u16* __restrict__ hi, u16* __restrict__ lo, int n4)
{
    const int stride = gridDim.x * 256;
    for (int i = blockIdx.x * 256 + threadIdx.x; i < n4; i += stride) {
        float4 v = ((const float4*)s)[i];
        u16 h0 = f2bf(v.x), h1 = f2bf(v.y), h2 = f2bf(v.z), h3 = f2bf(v.w);
        ((ushort4*)hi)[i] = make_ushort4(h0, h1, h2, h3);
        ((ushort4*)lo)[i] = make_ushort4(f2bf(v.x - bf2f(h0)), f2bf(v.y - bf2f(h1)),
                                         f2bf(v.z - bf2f(h2)), f2bf(v.w - bf2f(h3)));
    }
}
__global__ __launch_bounds__(256) void cvt_bf16_kernel(
    const float* __restrict__ s, u16* __restrict__ d, int n4)
{
    const int stride = gridDim.x * 256;
    for (int i = blockIdx.x * 256 + threadIdx.x; i < n4; i += stride) {
        float4 v = ((const float4*)s)[i];
        ((ushort4*)d)[i] = make_ushort4(f2bf(v.x), f2bf(v.y), f2bf(v.z), f2bf(v.w));
    }
}

// ---------------------------------------------------------------------------
extern "C" void kernel_launch(void* const* d_in, const int* in_sizes, int n_in,
                              void* d_out, int out_size, void* d_ws, size_t ws_size,
                              hipStream_t stream)
{
    const float* query   = (const float*)d_in[0];   // [B,Lq,D]
    const float* context = (const float*)d_in[1];   // [B,Lk,D]
    const int*   qlens   = (const int*)d_in[2];     // [B]
    const int*   clens   = (const int*)d_in[3];     // [B]
    const float* W_in    = (const float*)d_in[4];   // [D,D]
    const float* W_out   = (const float*)d_in[5];   // [D,2D]

    const int B = 32, Lq = 1024, Lk = 1024, D = 1024;
    const long long nQ = (long long)B * Lq * D;     // 33,554,432

    float* out    = (float*)d_out;                  // [B,Lq,D]
    float* scores = out + nQ;                       // [B,Lq,Lk]

    // workspace: 3x 64MiB bf16 planes + 8MiB weights + stats = 200.25 MiB
    u16* q_hi    = (u16*)d_ws;                      // 64 MiB
    u16* q_lo    = q_hi + nQ;                       // 64 MiB
    u16* mixb    = q_lo + nQ;                       // 64 MiB
    u16* w_in_hi = mixb + nQ;                       // 2 MiB
    u16* w_in_lo = w_in_hi + (1 << 20);             // 2 MiB
    u16* w_out_b = w_in_lo + (1 << 20);             // 4 MiB
    float2* stats = (float2*)(w_out_b + (2 << 20)); // 256 KiB

    // 0) weight prepasses (~6 us)
    cvt_hilo_kernel<<<1024, 256, 0, stream>>>(W_in, w_in_hi, w_in_lo, (D * D) / 4);
    cvt_bf16_kernel<<<2048, 256, 0, stream>>>(W_out, w_out_b, (D * 2 * D) / 4);

    // 1) q_hi/q_lo = split(query @ W_in^T)  (3-pass; B pre-split planes)
    mfma_gemm<3, false, false, false, 3, OP_F32, OP_PLANES>
        <<<dim3(D / BN, (B * Lq) / BM, 1), 256, 0, stream>>>(
        query, nullptr, w_in_hi, w_in_lo, q_hi, q_lo,
        D, D, D, D, 0LL, 0LL, 0LL, nullptr, 0LL, nullptr, nullptr);

    // 2) scores_m = mask(q @ ctx^T)  (batched NT, 3-pass; masked tiles skipped)
    mfma_gemm<1, false, false, false, 3, OP_PLANES, OP_F32>
        <<<dim3(Lk / BN, Lq / BM, B), 256, 0, stream>>>(
        q_hi, q_lo, context, nullptr, scores, nullptr,
        D, D, D, Lk, (long long)Lq * D, (long long)Lk * D, (long long)Lq * Lk,
        nullptr, 0LL, qlens, clens);

    // 3) per-row softmax stats
    row_stats_kernel<<<(B * Lq) / 4, 256, 0, stream>>>(scores, stats, Lk);

    // 4) mixb = bf16(softmax(scores) @ ctx)  (batched NN; zero-weight K skipped)
    mfma_gemm<4, true, false, true, 1, OP_F32, OP_F32>
        <<<dim3(D / BN, Lq / BM, B), 256, 0, stream>>>(
        scores, nullptr, context, nullptr, mixb, nullptr,
        Lk, Lk, D, D, (long long)Lq * Lk, (long long)Lk * D, (long long)Lq * D,
        stats, (long long)Lq, qlens, clens);

    // 5) out = tanh([mixb | q_hi] @ w_out_b^T)  (K=2048 split-A, all-bf16 operands)
    mfma_gemm<2, false, true, false, 1, OP_BF16, OP_BF16>
        <<<dim3(D / BN, (B * Lq) / BM, 1), 256, 0, stream>>>(
        mixb, q_hi, w_out_b, nullptr, out, nullptr,
        2 * D, D, 2 * D, D, 0LL, 0LL, 0LL, nullptr, 0LL, nullptr, nullptr);
}